// Round 1
// baseline (432.701 us; speedup 1.0000x reference)
//
#include <hip/hip_runtime.h>
#include <math.h>

#define EPSF 1e-7f
#define Bsz 2
#define Cch 1024
#define Hh 60
#define Ssz 3600
#define HID 256
#define TDIM 300
#define MH 473

// workspace layout (float offsets). total 93568 floats = 374 KB
#define OFF_MASK  0            // 2*3600   resized masks
#define OFF_SN2   7200         // 6*3600   sum over c of pooled^2  (atomic -> zeroed)
#define OFF_DOT   28800        // 6*3600   dotmaps                 (atomic -> zeroed)
#define OFF_ACC   50400        // 2*3600   normalized-sim accum    (atomic -> zeroed)
#define OFF_SCORE 57600        // 2*3600   attn scores/probs       (atomic -> zeroed)
#define OFF_WMAP  64800        // 6*3600   pool(inv_sn)
#define OFF_V     86400        // 6*1024   v[c] per (b,kt)
#define OFF_U     92544        // 2*256
#define OFF_KBAR  93056        // 2*256
#define ZERO_OFF  OFF_SN2
#define ZERO_CNT  (OFF_WMAP - OFF_SN2)   // 57600 floats

// ---------------- mask bilinear resize 473x473 -> 60x60 (align_corners) ----
__global__ void k_resize_mask(const float* __restrict__ masks, float* __restrict__ ws) {
    int idx = blockIdx.x * 256 + threadIdx.x;
    if (idx >= Bsz * Ssz) return;
    int b = idx / Ssz, q = idx - b * Ssz;
    int y = q / Hh, x = q - y * Hh;
    const float sc = (float)(MH - 1) / (float)(Hh - 1);   // exactly 8.0
    float py = y * sc, px = x * sc;
    int y0 = (int)floorf(py); int y1 = min(y0 + 1, MH - 1); float wy = py - y0;
    int x0 = (int)floorf(px); int x1 = min(x0 + 1, MH - 1); float wx = px - x0;
    const float* m = masks + (size_t)b * MH * MH;
    float v = m[y0 * MH + x0] * (1.f - wy) * (1.f - wx)
            + m[y1 * MH + x0] * wy * (1.f - wx)
            + m[y0 * MH + x1] * (1.f - wy) * wx
            + m[y1 * MH + x1] * wy * wx;
    ws[OFF_MASK + idx] = v;
}

// ---------------- pass A: sn2[b][kt][q] = sum_c pool_kt(supp_c*mask)(q)^2 --
// wave-per-channel sliding window: horizontal via shfl, vertical via register
// rings, squares accumulated in LDS (ds_add_f32), one global-atomic flush.
#define CPB 8
__global__ void __launch_bounds__(256) k_pool_sn2(const float* __restrict__ supp,
                                                  const float* __restrict__ ws_mask,
                                                  float* __restrict__ sn2g) {
    __shared__ float sl[3 * Ssz];          // 43200 B
    int tid = threadIdx.x;
    for (int i = tid; i < 3 * Ssz; i += 256) sl[i] = 0.f;
    __syncthreads();
    int b = blockIdx.y;
    int cg = blockIdx.x;                   // 0..127
    int wave = tid >> 6, lane = tid & 63;
    const float* mrow = ws_mask + (size_t)b * Ssz;
    for (int it = 0; it < CPB / 4; ++it) {
        int c = cg * CPB + it * 4 + wave;
        const float* sp = supp + ((size_t)b * Cch + c) * Ssz;
        float h5_0=0,h5_1=0,h5_2=0,h5_3=0,h5_4=0;       // hsum5 ring, rows yl-4..yl
        float r0=0,r1=0,r2=0,r3=0,r4=0,r5=0,r6=0;       // raw-val ring, rows yl-6..yl
        for (int yl = 0; yl < Hh + 3; ++yl) {
            float val = 0.f;
            if (yl < Hh && lane < Hh) val = sp[yl * Hh + lane] * mrow[yl * Hh + lane];
            int xm1 = lane - 1, xm2 = lane - 2, xm3 = lane - 3;
            float am1 = __shfl(val, max(xm1, 0), 64); if (xm1 < 0) am1 = 0.f;
            float am2 = __shfl(val, max(xm2, 0), 64); if (xm2 < 0) am2 = 0.f;
            float am3 = __shfl(val, max(xm3, 0), 64); if (xm3 < 0) am3 = 0.f;
            float ap1 = __shfl(val, min(lane + 1, 63), 64);
            float ap2 = __shfl(val, min(lane + 2, 63), 64);
            float ap3 = __shfl(val, min(lane + 3, 63), 64);
            float hsum5 = val + am1 + am2 + ap1 + ap2;
            float hsum7 = hsum5 + am3 + ap3;
            bool xok = lane < Hh;
            // kt2 = (1,7): horizontal only, output row yl
            if (xok && yl < Hh) {
                float t = hsum7 * (1.f / 7.f);
                atomicAdd(&sl[2 * Ssz + yl * Hh + lane], t * t);
            }
            // kt0 = (5,5): vertical ring over hsum5
            h5_0 = h5_1; h5_1 = h5_2; h5_2 = h5_3; h5_3 = h5_4; h5_4 = hsum5;
            int y0 = yl - 2;
            if (xok && y0 >= 0 && y0 < Hh) {
                float t = (h5_0 + h5_1 + h5_2 + h5_3 + h5_4) * (1.f / 25.f);
                atomicAdd(&sl[0 * Ssz + y0 * Hh + lane], t * t);
            }
            // kt1 = (7,1): vertical ring over raw vals
            r0 = r1; r1 = r2; r2 = r3; r3 = r4; r4 = r5; r5 = r6; r6 = val;
            int y1 = yl - 3;
            if (xok && y1 >= 0 && y1 < Hh) {
                float t = (r0 + r1 + r2 + r3 + r4 + r5 + r6) * (1.f / 7.f);
                atomicAdd(&sl[1 * Ssz + y1 * Hh + lane], t * t);
            }
        }
    }
    __syncthreads();
    float* g = sn2g + (size_t)b * 3 * Ssz;
    for (int i = tid; i < 3 * Ssz; i += 256) atomicAdd(&g[i], sl[i]);
}

// ---------------- wmap[b][kt] = pool_kt(1/sn) -------------------------------
__global__ void k_wmap(const float* __restrict__ sn2g, float* __restrict__ wmapg) {
    __shared__ float inv[Ssz];
    int bk = blockIdx.x;           // b*3+kt
    int kt = bk % 3;
    int tid = threadIdx.x;
    const float* sn2 = sn2g + (size_t)bk * Ssz;
    for (int i = tid; i < Ssz; i += 256)
        inv[i] = 1.0f / sqrtf(fmaxf(sn2[i], 1e-30f));
    __syncthreads();
    int kh = (kt == 0) ? 5 : (kt == 1) ? 7 : 1;
    int kw = (kt == 0) ? 5 : (kt == 2) ? 7 : 1;
    float norm = 1.f / (float)(kh * kw);
    int rh = kh / 2, rw = kw / 2;
    for (int q = tid; q < Ssz; q += 256) {
        int y = q / Hh, x = q - y * Hh;
        float s = 0.f;
        for (int dy = -rh; dy <= rh; ++dy) {
            int yy = y + dy; if (yy < 0 || yy >= Hh) continue;
            for (int dx = -rw; dx <= rw; ++dx) {
                int xx = x + dx; if (xx < 0 || xx >= Hh) continue;
                s += inv[yy * Hh + xx];
            }
        }
        wmapg[(size_t)bk * Ssz + q] = s * norm;
    }
}

// ---------------- v[b][kt][c] = sum_p supp*mask*wmap ------------------------
__global__ void k_v(const float* __restrict__ supp, float* __restrict__ ws) {
    int c = blockIdx.x, b = blockIdx.y;
    int tid = threadIdx.x;
    const float* sp = supp + ((size_t)b * Cch + c) * Ssz;
    const float* mrow = ws + OFF_MASK + (size_t)b * Ssz;
    const float* w0 = ws + OFF_WMAP + (size_t)(b * 3 + 0) * Ssz;
    const float* w1 = ws + OFF_WMAP + (size_t)(b * 3 + 1) * Ssz;
    const float* w2 = ws + OFF_WMAP + (size_t)(b * 3 + 2) * Ssz;
    float a0 = 0, a1 = 0, a2 = 0;
    for (int q = tid; q < Ssz; q += 256) {
        float s = sp[q] * mrow[q];
        a0 += s * w0[q]; a1 += s * w1[q]; a2 += s * w2[q];
    }
    __shared__ float red[3][256];
    red[0][tid] = a0; red[1][tid] = a1; red[2][tid] = a2;
    __syncthreads();
    for (int off = 128; off > 0; off >>= 1) {
        if (tid < off) {
            red[0][tid] += red[0][tid + off];
            red[1][tid] += red[1][tid + off];
            red[2][tid] += red[2][tid + off];
        }
        __syncthreads();
    }
    if (tid == 0) {
        ws[OFF_V + (size_t)(b * 3 + 0) * Cch + c] = red[0][0];
        ws[OFF_V + (size_t)(b * 3 + 1) * Cch + c] = red[1][0];
        ws[OFF_V + (size_t)(b * 3 + 2) * Cch + c] = red[2][0];
    }
}

// ---------------- dot[b][kt][q] = sum_c query[c,q]*v[kt][c] -----------------
__global__ void k_dot(const float* __restrict__ query, float* __restrict__ ws) {
    int qt = blockIdx.x, cc = blockIdx.y, b = blockIdx.z;
    int q = qt * 256 + threadIdx.x;
    if (q >= Ssz) return;
    const float* v0 = ws + OFF_V + (size_t)(b * 3 + 0) * Cch;
    const float* v1 = ws + OFF_V + (size_t)(b * 3 + 1) * Cch;
    const float* v2 = ws + OFF_V + (size_t)(b * 3 + 2) * Cch;
    float a0 = 0, a1 = 0, a2 = 0;
    int c0 = cc * 64;
    for (int c = c0; c < c0 + 64; ++c) {
        float qv = query[((size_t)b * Cch + c) * Ssz + q];
        a0 += qv * v0[c]; a1 += qv * v1[c]; a2 += qv * v2[c];
    }
    atomicAdd(&ws[OFF_DOT + (size_t)(b * 3 + 0) * Ssz + q], a0);
    atomicAdd(&ws[OFF_DOT + (size_t)(b * 3 + 1) * Ssz + q], a1);
    atomicAdd(&ws[OFF_DOT + (size_t)(b * 3 + 2) * Ssz + q], a2);
}

// ---------------- sim = pool(dot)/(khkw*S); minmax-normalize; accumulate ----
__global__ void k_sim(float* __restrict__ ws) {
    __shared__ float d[Ssz];
    __shared__ float red[256];
    int bk = blockIdx.x; int b = bk / 3; int kt = bk % 3;
    int tid = threadIdx.x;
    const float* dg = ws + OFF_DOT + (size_t)bk * Ssz;
    for (int i = tid; i < Ssz; i += 256) d[i] = dg[i];
    __syncthreads();
    int kh = (kt == 0) ? 5 : (kt == 1) ? 7 : 1;
    int kw = (kt == 0) ? 5 : (kt == 2) ? 7 : 1;
    int rh = kh / 2, rw = kw / 2;
    float norm = 1.f / ((float)(kh * kw) * (float)Ssz);
    float vals[15];
    float vmin = INFINITY, vmax = -INFINITY;
    for (int j = 0; j < 15; ++j) {
        int q = tid + j * 256;
        if (q < Ssz) {
            int y = q / Hh, x = q - y * Hh;
            float s = 0.f;
            for (int dy = -rh; dy <= rh; ++dy) {
                int yy = y + dy; if (yy < 0 || yy >= Hh) continue;
                for (int dx = -rw; dx <= rw; ++dx) {
                    int xx = x + dx; if (xx < 0 || xx >= Hh) continue;
                    s += d[yy * Hh + xx];
                }
            }
            float val = s * norm;
            vals[j] = val;
            vmin = fminf(vmin, val); vmax = fmaxf(vmax, val);
        }
    }
    red[tid] = vmin; __syncthreads();
    for (int off = 128; off > 0; off >>= 1) {
        if (tid < off) red[tid] = fminf(red[tid], red[tid + off]);
        __syncthreads();
    }
    float mn = red[0]; __syncthreads();
    red[tid] = vmax; __syncthreads();
    for (int off = 128; off > 0; off >>= 1) {
        if (tid < off) red[tid] = fmaxf(red[tid], red[tid + off]);
        __syncthreads();
    }
    float mx = red[0];
    float inv = 1.f / (mx - mn + EPSF);
    for (int j = 0; j < 15; ++j) {
        int q = tid + j * 256;
        if (q < Ssz) atomicAdd(&ws[OFF_ACC + (size_t)b * Ssz + q], (vals[j] - mn) * inv);
    }
}

// ---------------- corr1 + bilinear downsamples ------------------------------
__global__ void k_final(const float* __restrict__ weight, const float* __restrict__ ws,
                        float* __restrict__ out) {
    int idx = blockIdx.x * 256 + threadIdx.x;
    if (idx < Bsz * Ssz) {
        int b = idx / Ssz, q = idx - b * Ssz;
        out[idx] = weight[b] * (1.f / 3.f) * ws[OFF_ACC + (size_t)b * Ssz + q];
        return;
    }
    int r = idx - Bsz * Ssz;
    int O, outbase;
    if (r < 1800)       { O = 30; outbase = 7200; }
    else if (r < 2250)  { O = 15; outbase = 9000; r -= 1800; }
    else if (r < 2378)  { O = 8;  outbase = 9450; r -= 2250; }
    else return;
    int n = O * O;
    int b = r / n, p = r - b * n;
    int y = p / O, x = p - y * O;
    float sc = (float)(Hh - 1) / (float)(O - 1);
    float py = y * sc, px = x * sc;
    int y0 = (int)floorf(py), x0 = (int)floorf(px);
    int y1 = min(y0 + 1, Hh - 1), x1 = min(x0 + 1, Hh - 1);
    float wy = py - y0, wx = px - x0;
    const float* src = ws + OFF_ACC + (size_t)b * Ssz;
    float v = src[y0 * Hh + x0] * (1.f - wy) * (1.f - wx)
            + src[y1 * Hh + x0] * wy * (1.f - wx)
            + src[y0 * Hh + x1] * (1.f - wy) * wx
            + src[y1 * Hh + x1] * wy * wx;
    out[outbase + r] = v * weight[b] * (1.f / 3.f);
}

// ---------------- APA: u = w_k^T (w_bl^T (w_q^T [text;proto])) --------------
__global__ void k_apa_u(const float* __restrict__ text, const float* __restrict__ proto,
                        const float* __restrict__ w_q, const float* __restrict__ w_bl,
                        const float* __restrict__ w_k, float* __restrict__ ws) {
    int b = blockIdx.x; int tid = threadIdx.x;   // 256 threads
    __shared__ float qx[HID], qw[HID];
    float acc = 0.f;
    for (int e = 0; e < TDIM + HID; ++e) {
        float qe = (e < TDIM) ? text[b * TDIM + e] : proto[b * HID + e - TDIM];
        acc += qe * w_q[(size_t)e * HID + tid];
    }
    qx[tid] = acc; __syncthreads();
    acc = 0.f;
    for (int h = 0; h < HID; ++h) acc += qx[h] * w_bl[(size_t)h * HID + tid];
    qw[tid] = acc; __syncthreads();
    acc = 0.f;
    for (int dd = 0; dd < HID; ++dd) acc += qw[dd] * w_k[(size_t)dd * HID + tid];
    ws[OFF_U + b * HID + tid] = acc;
}

// ---------------- score[b,s] = sum_i u[i] * k[b,i,s] ------------------------
__global__ void k_score(const float* __restrict__ kin, float* __restrict__ ws) {
    int st = blockIdx.x, ic = blockIdx.y, b = blockIdx.z;
    int s = st * 256 + threadIdx.x;
    if (s >= Ssz) return;
    const float* u = ws + OFF_U + b * HID;
    float acc = 0.f;
    int i0 = ic * 64;
    for (int i = i0; i < i0 + 64; ++i)
        acc += u[i] * kin[((size_t)b * HID + i) * Ssz + s];
    atomicAdd(&ws[OFF_SCORE + (size_t)b * Ssz + s], acc);
}

// ---------------- softmax over 3600, in place -------------------------------
__global__ void k_softmax(float* __restrict__ ws) {
    int b = blockIdx.x; int tid = threadIdx.x;
    __shared__ float red[256];
    float* sc = ws + OFF_SCORE + (size_t)b * Ssz;
    float vals[15];
    float mx = -INFINITY;
    for (int j = 0; j < 15; ++j) {
        int s = tid + j * 256;
        if (s < Ssz) { vals[j] = sc[s]; mx = fmaxf(mx, vals[j]); }
    }
    red[tid] = mx; __syncthreads();
    for (int off = 128; off > 0; off >>= 1) {
        if (tid < off) red[tid] = fmaxf(red[tid], red[tid + off]);
        __syncthreads();
    }
    mx = red[0]; __syncthreads();
    float sum = 0.f;
    for (int j = 0; j < 15; ++j) {
        int s = tid + j * 256;
        if (s < Ssz) { vals[j] = expf(vals[j] - mx); sum += vals[j]; }
    }
    red[tid] = sum; __syncthreads();
    for (int off = 128; off > 0; off >>= 1) {
        if (tid < off) red[tid] += red[tid + off];
        __syncthreads();
    }
    float inv = 1.f / red[0];
    for (int j = 0; j < 15; ++j) {
        int s = tid + j * 256;
        if (s < Ssz) sc[s] = vals[j] * inv;
    }
}

// ---------------- kbar[b,i] = sum_s p[s]*k[b,i,s] ---------------------------
__global__ void k_kbar(const float* __restrict__ kin, float* __restrict__ ws) {
    int i = blockIdx.x, b = blockIdx.y;
    int tid = threadIdx.x;
    const float* p = ws + OFF_SCORE + (size_t)b * Ssz;
    const float* kr = kin + ((size_t)b * HID + i) * Ssz;
    float acc = 0.f;
    for (int s = tid; s < Ssz; s += 256) acc += p[s] * kr[s];
    __shared__ float red[256];
    red[tid] = acc; __syncthreads();
    for (int off = 128; off > 0; off >>= 1) {
        if (tid < off) red[tid] += red[tid + off];
        __syncthreads();
    }
    if (tid == 0) ws[OFF_KBAR + b * HID + i] = red[0];
}

// ---------------- out = w_proj^T (w_k kbar) + b + proto ---------------------
__global__ void k_apa_out(const float* __restrict__ w_k, const float* __restrict__ w_proj,
                          const float* __restrict__ b_proj, const float* __restrict__ proto,
                          const float* __restrict__ ws, float* __restrict__ out) {
    int b = blockIdx.x, tid = threadIdx.x;
    __shared__ float o1[HID];
    const float* kb = ws + OFF_KBAR + b * HID;
    float acc = 0.f;
    for (int i = 0; i < HID; ++i) acc += w_k[(size_t)tid * HID + i] * kb[i];
    o1[tid] = acc; __syncthreads();
    acc = 0.f;
    for (int dd = 0; dd < HID; ++dd) acc += o1[dd] * w_proj[(size_t)dd * HID + tid];
    out[9578 + b * HID + tid] = acc + b_proj[tid] + proto[b * HID + tid];
}

extern "C" void kernel_launch(void* const* d_in, const int* in_sizes, int n_in,
                              void* d_out, int out_size, void* d_ws, size_t ws_size,
                              hipStream_t stream) {
    const float* weight = (const float*)d_in[0];
    const float* query  = (const float*)d_in[1];
    const float* supp   = (const float*)d_in[2];
    const float* masks  = (const float*)d_in[3];
    const float* kin    = (const float*)d_in[4];
    const float* text   = (const float*)d_in[5];
    const float* proto  = (const float*)d_in[6];
    const float* w_q    = (const float*)d_in[7];
    const float* w_k    = (const float*)d_in[8];
    const float* w_bl   = (const float*)d_in[9];
    const float* w_proj = (const float*)d_in[10];
    const float* b_proj = (const float*)d_in[11];
    float* out = (float*)d_out;
    float* ws  = (float*)d_ws;

    // zero atomic-accumulated regions (ws is poisoned 0xAA before every call)
    hipMemsetAsync(ws + ZERO_OFF, 0, (size_t)ZERO_CNT * sizeof(float), stream);

    k_resize_mask<<<(Bsz * Ssz + 255) / 256, 256, 0, stream>>>(masks, ws);
    k_pool_sn2<<<dim3(Cch / CPB, Bsz), 256, 0, stream>>>(supp, ws + OFF_MASK, ws + OFF_SN2);
    k_wmap<<<6, 256, 0, stream>>>(ws + OFF_SN2, ws + OFF_WMAP);
    k_v<<<dim3(Cch, Bsz), 256, 0, stream>>>(supp, ws);
    k_dot<<<dim3(15, Cch / 64, Bsz), 256, 0, stream>>>(query, ws);
    k_sim<<<6, 256, 0, stream>>>(ws);
    k_final<<<(Bsz * Ssz + 2378 + 255) / 256, 256, 0, stream>>>(weight, ws, out);

    k_apa_u<<<Bsz, 256, 0, stream>>>(text, proto, w_q, w_bl, w_k, ws);
    k_score<<<dim3(15, 4, Bsz), 256, 0, stream>>>(kin, ws);
    k_softmax<<<Bsz, 256, 0, stream>>>(ws);
    k_kbar<<<dim3(HID, Bsz), 256, 0, stream>>>(kin, ws);
    k_apa_out<<<Bsz, 256, 0, stream>>>(w_k, w_proj, b_proj, proto, ws, out);
}

// Round 2
// 359.517 us; speedup vs baseline: 1.2036x; 1.2036x over previous
//
#include <hip/hip_runtime.h>
#include <math.h>

#define EPSF 1e-7f
#define Bsz 2
#define Cch 1024
#define Hh 60
#define Ssz 3600
#define HID 256
#define TDIM 300
#define MH 473

// pool tiling
#define TROWS 15
#define LROWS 21          // TROWS + 6 halo
#define LPITCH 68         // 4-offset zero pad on both sides of 60 cols
#define CPG 16            // channels per block

// workspace layout (float offsets). total 93568 floats = 374 KB
#define OFF_MASK  0            // 2*3600   resized masks
#define OFF_SN2   7200         // 6*3600   sum over c of pooled^2  (atomic -> zeroed)
#define OFF_DOT   28800        // 6*3600   dotmaps                 (atomic -> zeroed)
#define OFF_ACC   50400        // 2*3600   normalized-sim accum    (atomic -> zeroed)
#define OFF_SCORE 57600        // 2*3600   attn scores/probs       (atomic -> zeroed)
#define OFF_WMAP  64800        // 6*3600   pool(inv_sn)
#define OFF_V     86400        // 6*1024   v[c] per (b,kt)
#define OFF_U     92544        // 2*256
#define OFF_KBAR  93056        // 2*256
#define ZERO_OFF  OFF_SN2
#define ZERO_CNT  (OFF_WMAP - OFF_SN2)   // 57600 floats

// ---------------- mask bilinear resize 473x473 -> 60x60 (align_corners) ----
__global__ void k_resize_mask(const float* __restrict__ masks, float* __restrict__ ws) {
    int idx = blockIdx.x * 256 + threadIdx.x;
    if (idx >= Bsz * Ssz) return;
    int b = idx / Ssz, q = idx - b * Ssz;
    int y = q / Hh, x = q - y * Hh;
    const float sc = (float)(MH - 1) / (float)(Hh - 1);   // exactly 8.0
    float py = y * sc, px = x * sc;
    int y0 = (int)floorf(py); int y1 = min(y0 + 1, MH - 1); float wy = py - y0;
    int x0 = (int)floorf(px); int x1 = min(x0 + 1, MH - 1); float wx = px - x0;
    const float* m = masks + (size_t)b * MH * MH;
    float v = m[y0 * MH + x0] * (1.f - wy) * (1.f - wx)
            + m[y1 * MH + x0] * wy * (1.f - wx)
            + m[y0 * MH + x1] * (1.f - wy) * wx
            + m[y1 * MH + x1] * wy * wx;
    ws[OFF_MASK + idx] = v;
}

// ---------------- pass A: sn2[b][kt][q] = sum_c pool_kt(supp_c*mask)(q)^2 --
// Tile-based: block = (row-tile, channel-group, b). Threads own output pixels,
// accumulate squares in REGISTERS across 16 channels; separable hsums staged
// in LDS; next channel's patch prefetched into registers; one atomic flush.
__global__ void __launch_bounds__(256) k_pool_sn2(const float* __restrict__ supp,
                                                  const float* __restrict__ ws_mask,
                                                  float* __restrict__ sn2g) {
    __shared__ float mk[LROWS * LPITCH];
    __shared__ float raw[LROWS * LPITCH];
    __shared__ float hs5[LROWS * LPITCH];
    __shared__ float hs7[LROWS * LPITCH];
    int tid = threadIdx.x;
    int tile = blockIdx.x;       // 0..3
    int cg = blockIdx.y;         // 0..63
    int b = blockIdx.z;          // 0..1
    int y0 = tile * TROWS;

    for (int i = tid; i < LROWS * LPITCH; i += 256) {
        mk[i] = 0.f; raw[i] = 0.f; hs5[i] = 0.f; hs7[i] = 0.f;
    }
    __syncthreads();

    // per-thread load coordinates (1260 patch elements, 5 slots/thread)
    int lr[5], lx[5]; bool lv[5], la[5];
    #pragma unroll
    for (int j = 0; j < 5; ++j) {
        int idx = tid + 256 * j;
        int r = idx / 60, x = idx - 60 * r;
        lr[j] = r; lx[j] = x;
        la[j] = idx < 1260;
        int iy = y0 - 3 + r;
        lv[j] = la[j] && (iy >= 0) && (iy < Hh);
    }
    // mask tile into LDS
    const float* mrow = ws_mask + (size_t)b * Ssz;
    #pragma unroll
    for (int j = 0; j < 5; ++j)
        if (lv[j]) mk[lr[j] * LPITCH + 4 + lx[j]] = mrow[(y0 - 3 + lr[j]) * 60 + lx[j]];

    // per-thread output coordinates (900 outputs, 4 slots/thread)
    int orow[4], ox[4]; bool ov[4];
    #pragma unroll
    for (int j = 0; j < 4; ++j) {
        int o = tid + 256 * j;
        int oy = o / 60, x = o - 60 * oy;
        orow[j] = oy + 3; ox[j] = x; ov[j] = o < 900;
    }
    float a0[4] = {0,0,0,0}, a1[4] = {0,0,0,0}, a2[4] = {0,0,0,0};

    const float* chbase = supp + ((size_t)b * Cch + (size_t)cg * CPG) * Ssz + (y0 - 3) * 60;
    float pf[5];
    #pragma unroll
    for (int j = 0; j < 5; ++j) pf[j] = lv[j] ? chbase[tid + 256 * j] : 0.f;

    for (int c = 0; c < CPG; ++c) {
        __syncthreads();   // prev iteration's LDS consumers done (and mask visible on c==0)
        #pragma unroll
        for (int j = 0; j < 5; ++j)
            if (lv[j]) raw[lr[j] * LPITCH + 4 + lx[j]] = pf[j] * mk[lr[j] * LPITCH + 4 + lx[j]];
        __syncthreads();
        // horizontal sums
        #pragma unroll
        for (int j = 0; j < 5; ++j)
            if (la[j]) {
                int base = lr[j] * LPITCH + 4 + lx[j];
                float m3 = raw[base - 3], m2 = raw[base - 2], m1 = raw[base - 1];
                float c0 = raw[base], p1 = raw[base + 1], p2 = raw[base + 2], p3 = raw[base + 3];
                float h5 = m2 + m1 + c0 + p1 + p2;
                hs5[base] = h5;
                hs7[base] = h5 + m3 + p3;
            }
        __syncthreads();
        // prefetch next channel while we compute outputs
        if (c + 1 < CPG) {
            const float* nb = chbase + (size_t)(c + 1) * Ssz;
            #pragma unroll
            for (int j = 0; j < 5; ++j) pf[j] = lv[j] ? nb[tid + 256 * j] : 0.f;
        }
        // vertical sums + square + register accumulate
        #pragma unroll
        for (int j = 0; j < 4; ++j)
            if (ov[j]) {
                int base = orow[j] * LPITCH + 4 + ox[j];
                float p55 = hs5[base - 2*LPITCH] + hs5[base - LPITCH] + hs5[base]
                          + hs5[base + LPITCH] + hs5[base + 2*LPITCH];
                float p71 = raw[base - 3*LPITCH] + raw[base - 2*LPITCH] + raw[base - LPITCH]
                          + raw[base] + raw[base + LPITCH] + raw[base + 2*LPITCH] + raw[base + 3*LPITCH];
                float p17 = hs7[base];
                p55 *= (1.f / 25.f); p71 *= (1.f / 7.f); p17 *= (1.f / 7.f);
                a0[j] += p55 * p55; a1[j] += p71 * p71; a2[j] += p17 * p17;
            }
    }
    // flush
    float* g0 = sn2g + ((size_t)b * 3 + 0) * Ssz;
    float* g1 = sn2g + ((size_t)b * 3 + 1) * Ssz;
    float* g2 = sn2g + ((size_t)b * 3 + 2) * Ssz;
    #pragma unroll
    for (int j = 0; j < 4; ++j)
        if (ov[j]) {
            int q = (y0 + orow[j] - 3) * 60 + ox[j];
            atomicAdd(&g0[q], a0[j]);
            atomicAdd(&g1[q], a1[j]);
            atomicAdd(&g2[q], a2[j]);
        }
}

// ---------------- wmap[b][kt] = pool_kt(1/sn), row-tiled ------------------
__global__ void k_wmap(const float* __restrict__ sn2g, float* __restrict__ wmapg) {
    __shared__ float inv[LROWS * LPITCH];
    int tile = blockIdx.x;       // 0..3
    int bk = blockIdx.y;         // 0..5 = b*3+kt
    int kt = bk % 3;
    int tid = threadIdx.x;
    int y0 = tile * TROWS;
    for (int i = tid; i < LROWS * LPITCH; i += 256) inv[i] = 0.f;
    __syncthreads();
    const float* sn2 = sn2g + (size_t)bk * Ssz;
    #pragma unroll
    for (int j = 0; j < 5; ++j) {
        int idx = tid + 256 * j;
        if (idx < 1260) {
            int r = idx / 60, x = idx - 60 * r;
            int iy = y0 - 3 + r;
            if (iy >= 0 && iy < Hh)
                inv[r * LPITCH + 4 + x] = 1.0f / sqrtf(fmaxf(sn2[iy * 60 + x], 1e-30f));
        }
    }
    __syncthreads();
    int kh = (kt == 0) ? 5 : (kt == 1) ? 7 : 1;
    int kw = (kt == 0) ? 5 : (kt == 2) ? 7 : 1;
    int rh = kh / 2, rw = kw / 2;
    float norm = 1.f / (float)(kh * kw);
    #pragma unroll
    for (int j = 0; j < 4; ++j) {
        int o = tid + 256 * j;
        if (o < 900) {
            int oy = o / 60, x = o - 60 * oy;
            int base = (oy + 3) * LPITCH + 4 + x;
            float s = 0.f;
            for (int dy = -rh; dy <= rh; ++dy)
                for (int dx = -rw; dx <= rw; ++dx)
                    s += inv[base + dy * LPITCH + dx];
            wmapg[(size_t)bk * Ssz + (y0 + oy) * 60 + x] = s * norm;
        }
    }
}

// ---------------- v[b][kt][c] = sum_p supp*mask*wmap ------------------------
__global__ void k_v(const float* __restrict__ supp, float* __restrict__ ws) {
    int c = blockIdx.x, b = blockIdx.y;
    int tid = threadIdx.x;
    const float* sp = supp + ((size_t)b * Cch + c) * Ssz;
    const float* mrow = ws + OFF_MASK + (size_t)b * Ssz;
    const float* w0 = ws + OFF_WMAP + (size_t)(b * 3 + 0) * Ssz;
    const float* w1 = ws + OFF_WMAP + (size_t)(b * 3 + 1) * Ssz;
    const float* w2 = ws + OFF_WMAP + (size_t)(b * 3 + 2) * Ssz;
    float a0 = 0, a1 = 0, a2 = 0;
    for (int q = tid; q < Ssz; q += 256) {
        float s = sp[q] * mrow[q];
        a0 += s * w0[q]; a1 += s * w1[q]; a2 += s * w2[q];
    }
    __shared__ float red[3][256];
    red[0][tid] = a0; red[1][tid] = a1; red[2][tid] = a2;
    __syncthreads();
    for (int off = 128; off > 0; off >>= 1) {
        if (tid < off) {
            red[0][tid] += red[0][tid + off];
            red[1][tid] += red[1][tid + off];
            red[2][tid] += red[2][tid + off];
        }
        __syncthreads();
    }
    if (tid == 0) {
        ws[OFF_V + (size_t)(b * 3 + 0) * Cch + c] = red[0][0];
        ws[OFF_V + (size_t)(b * 3 + 1) * Cch + c] = red[1][0];
        ws[OFF_V + (size_t)(b * 3 + 2) * Cch + c] = red[2][0];
    }
}

// ---------------- dot[b][kt][q] = sum_c query[c,q]*v[kt][c] -----------------
__global__ void k_dot(const float* __restrict__ query, float* __restrict__ ws) {
    int qt = blockIdx.x, cc = blockIdx.y, b = blockIdx.z;
    int q = qt * 256 + threadIdx.x;
    if (q >= Ssz) return;
    const float* v0 = ws + OFF_V + (size_t)(b * 3 + 0) * Cch;
    const float* v1 = ws + OFF_V + (size_t)(b * 3 + 1) * Cch;
    const float* v2 = ws + OFF_V + (size_t)(b * 3 + 2) * Cch;
    float a0 = 0, a1 = 0, a2 = 0;
    int c0 = cc * 64;
    for (int c = c0; c < c0 + 64; ++c) {
        float qv = query[((size_t)b * Cch + c) * Ssz + q];
        a0 += qv * v0[c]; a1 += qv * v1[c]; a2 += qv * v2[c];
    }
    atomicAdd(&ws[OFF_DOT + (size_t)(b * 3 + 0) * Ssz + q], a0);
    atomicAdd(&ws[OFF_DOT + (size_t)(b * 3 + 1) * Ssz + q], a1);
    atomicAdd(&ws[OFF_DOT + (size_t)(b * 3 + 2) * Ssz + q], a2);
}

// ---------------- sim = pool(dot)/(khkw*S); minmax-normalize; accumulate ----
__global__ void k_sim(float* __restrict__ ws) {
    __shared__ float d[Ssz];
    __shared__ float red[256];
    int bk = blockIdx.x; int b = bk / 3; int kt = bk % 3;
    int tid = threadIdx.x;
    const float* dg = ws + OFF_DOT + (size_t)bk * Ssz;
    for (int i = tid; i < Ssz; i += 256) d[i] = dg[i];
    __syncthreads();
    int kh = (kt == 0) ? 5 : (kt == 1) ? 7 : 1;
    int kw = (kt == 0) ? 5 : (kt == 2) ? 7 : 1;
    int rh = kh / 2, rw = kw / 2;
    float norm = 1.f / ((float)(kh * kw) * (float)Ssz);
    float vals[15];
    float vmin = INFINITY, vmax = -INFINITY;
    for (int j = 0; j < 15; ++j) {
        int q = tid + j * 256;
        if (q < Ssz) {
            int y = q / Hh, x = q - y * Hh;
            float s = 0.f;
            for (int dy = -rh; dy <= rh; ++dy) {
                int yy = y + dy; if (yy < 0 || yy >= Hh) continue;
                for (int dx = -rw; dx <= rw; ++dx) {
                    int xx = x + dx; if (xx < 0 || xx >= Hh) continue;
                    s += d[yy * Hh + xx];
                }
            }
            float val = s * norm;
            vals[j] = val;
            vmin = fminf(vmin, val); vmax = fmaxf(vmax, val);
        }
    }
    red[tid] = vmin; __syncthreads();
    for (int off = 128; off > 0; off >>= 1) {
        if (tid < off) red[tid] = fminf(red[tid], red[tid + off]);
        __syncthreads();
    }
    float mn = red[0]; __syncthreads();
    red[tid] = vmax; __syncthreads();
    for (int off = 128; off > 0; off >>= 1) {
        if (tid < off) red[tid] = fmaxf(red[tid], red[tid + off]);
        __syncthreads();
    }
    float mx = red[0];
    float inv = 1.f / (mx - mn + EPSF);
    for (int j = 0; j < 15; ++j) {
        int q = tid + j * 256;
        if (q < Ssz) atomicAdd(&ws[OFF_ACC + (size_t)b * Ssz + q], (vals[j] - mn) * inv);
    }
}

// ---------------- corr1 + bilinear downsamples ------------------------------
__global__ void k_final(const float* __restrict__ weight, const float* __restrict__ ws,
                        float* __restrict__ out) {
    int idx = blockIdx.x * 256 + threadIdx.x;
    if (idx < Bsz * Ssz) {
        int b = idx / Ssz, q = idx - b * Ssz;
        out[idx] = weight[b] * (1.f / 3.f) * ws[OFF_ACC + (size_t)b * Ssz + q];
        return;
    }
    int r = idx - Bsz * Ssz;
    int O, outbase;
    if (r < 1800)       { O = 30; outbase = 7200; }
    else if (r < 2250)  { O = 15; outbase = 9000; r -= 1800; }
    else if (r < 2378)  { O = 8;  outbase = 9450; r -= 2250; }
    else return;
    int n = O * O;
    int b = r / n, p = r - b * n;
    int y = p / O, x = p - y * O;
    float sc = (float)(Hh - 1) / (float)(O - 1);
    float py = y * sc, px = x * sc;
    int y0 = (int)floorf(py), x0 = (int)floorf(px);
    int y1 = min(y0 + 1, Hh - 1), x1 = min(x0 + 1, Hh - 1);
    float wy = py - y0, wx = px - x0;
    const float* src = ws + OFF_ACC + (size_t)b * Ssz;
    float v = src[y0 * Hh + x0] * (1.f - wy) * (1.f - wx)
            + src[y1 * Hh + x0] * wy * (1.f - wx)
            + src[y0 * Hh + x1] * (1.f - wy) * wx
            + src[y1 * Hh + x1] * wy * wx;
    out[outbase + r] = v * weight[b] * (1.f / 3.f);
}

// ---------------- APA: u = w_k^T (w_bl^T (w_q^T [text;proto])) --------------
// 1024 threads, 4-way split-K per stage + LDS reduce
__global__ void k_apa_u(const float* __restrict__ text, const float* __restrict__ proto,
                        const float* __restrict__ w_q, const float* __restrict__ w_bl,
                        const float* __restrict__ w_k, float* __restrict__ ws) {
    int b = blockIdx.x; int tid = threadIdx.x;   // 1024
    int h = tid & 255, p = tid >> 8;
    __shared__ float part[4][256];
    __shared__ float qx[256], qw[256];
    float acc = 0.f;
    for (int e = p; e < TDIM + HID; e += 4) {
        float qe = (e < TDIM) ? text[b * TDIM + e] : proto[b * HID + e - TDIM];
        acc += qe * w_q[(size_t)e * HID + h];
    }
    part[p][h] = acc; __syncthreads();
    if (p == 0) qx[h] = part[0][h] + part[1][h] + part[2][h] + part[3][h];
    __syncthreads();
    acc = 0.f;
    for (int e = p; e < HID; e += 4) acc += qx[e] * w_bl[(size_t)e * HID + h];
    part[p][h] = acc; __syncthreads();
    if (p == 0) qw[h] = part[0][h] + part[1][h] + part[2][h] + part[3][h];
    __syncthreads();
    acc = 0.f;
    for (int e = p; e < HID; e += 4) acc += qw[e] * w_k[(size_t)e * HID + h];
    part[p][h] = acc; __syncthreads();
    if (p == 0) ws[OFF_U + b * HID + h] = part[0][h] + part[1][h] + part[2][h] + part[3][h];
}

// ---------------- score[b,s] = sum_i u[i] * k[b,i,s] ------------------------
__global__ void k_score(const float* __restrict__ kin, float* __restrict__ ws) {
    int st = blockIdx.x, ic = blockIdx.y, b = blockIdx.z;
    int s = st * 256 + threadIdx.x;
    if (s >= Ssz) return;
    const float* u = ws + OFF_U + b * HID;
    float acc = 0.f;
    int i0 = ic * 64;
    for (int i = i0; i < i0 + 64; ++i)
        acc += u[i] * kin[((size_t)b * HID + i) * Ssz + s];
    atomicAdd(&ws[OFF_SCORE + (size_t)b * Ssz + s], acc);
}

// ---------------- softmax over 3600, in place -------------------------------
__global__ void k_softmax(float* __restrict__ ws) {
    int b = blockIdx.x; int tid = threadIdx.x;
    __shared__ float red[256];
    float* sc = ws + OFF_SCORE + (size_t)b * Ssz;
    float vals[15];
    float mx = -INFINITY;
    for (int j = 0; j < 15; ++j) {
        int s = tid + j * 256;
        if (s < Ssz) { vals[j] = sc[s]; mx = fmaxf(mx, vals[j]); }
    }
    red[tid] = mx; __syncthreads();
    for (int off = 128; off > 0; off >>= 1) {
        if (tid < off) red[tid] = fmaxf(red[tid], red[tid + off]);
        __syncthreads();
    }
    mx = red[0]; __syncthreads();
    float sum = 0.f;
    for (int j = 0; j < 15; ++j) {
        int s = tid + j * 256;
        if (s < Ssz) { vals[j] = expf(vals[j] - mx); sum += vals[j]; }
    }
    red[tid] = sum; __syncthreads();
    for (int off = 128; off > 0; off >>= 1) {
        if (tid < off) red[tid] += red[tid + off];
        __syncthreads();
    }
    float inv = 1.f / red[0];
    for (int j = 0; j < 15; ++j) {
        int s = tid + j * 256;
        if (s < Ssz) sc[s] = vals[j] * inv;
    }
}

// ---------------- kbar[b,i] = sum_s p[s]*k[b,i,s] ---------------------------
__global__ void k_kbar(const float* __restrict__ kin, float* __restrict__ ws) {
    int i = blockIdx.x, b = blockIdx.y;
    int tid = threadIdx.x;
    const float* p = ws + OFF_SCORE + (size_t)b * Ssz;
    const float* kr = kin + ((size_t)b * HID + i) * Ssz;
    float acc = 0.f;
    for (int s = tid; s < Ssz; s += 256) acc += p[s] * kr[s];
    __shared__ float red[256];
    red[tid] = acc; __syncthreads();
    for (int off = 128; off > 0; off >>= 1) {
        if (tid < off) red[tid] += red[tid + off];
        __syncthreads();
    }
    if (tid == 0) ws[OFF_KBAR + b * HID + i] = red[0];
}

// ---------------- out = w_proj^T (w_k kbar) + b + proto ---------------------
// 1024 threads: 4 threads per row for o1, 4-way split for o2
__global__ void k_apa_out(const float* __restrict__ w_k, const float* __restrict__ w_proj,
                          const float* __restrict__ b_proj, const float* __restrict__ proto,
                          const float* __restrict__ ws, float* __restrict__ out) {
    int b = blockIdx.x, tid = threadIdx.x;   // 1024
    __shared__ float kb[256], o1[256];
    __shared__ float part[4][256];
    if (tid < 256) kb[tid] = ws[OFF_KBAR + b * HID + tid];
    __syncthreads();
    int h2 = tid >> 2, sub = tid & 3;
    float acc = 0.f;
    for (int i = sub; i < HID; i += 4) acc += w_k[(size_t)h2 * HID + i] * kb[i];
    part[sub][h2] = acc; __syncthreads();
    if (tid < 256) o1[tid] = part[0][tid] + part[1][tid] + part[2][tid] + part[3][tid];
    __syncthreads();
    int h = tid & 255, p = tid >> 8;
    float a2 = 0.f;
    for (int d = p; d < HID; d += 4) a2 += o1[d] * w_proj[(size_t)d * HID + h];
    part[p][h] = a2; __syncthreads();
    if (p == 0)
        out[9578 + b * HID + h] = part[0][h] + part[1][h] + part[2][h] + part[3][h]
                                + b_proj[h] + proto[b * HID + h];
}

extern "C" void kernel_launch(void* const* d_in, const int* in_sizes, int n_in,
                              void* d_out, int out_size, void* d_ws, size_t ws_size,
                              hipStream_t stream) {
    const float* weight = (const float*)d_in[0];
    const float* query  = (const float*)d_in[1];
    const float* supp   = (const float*)d_in[2];
    const float* masks  = (const float*)d_in[3];
    const float* kin    = (const float*)d_in[4];
    const float* text   = (const float*)d_in[5];
    const float* proto  = (const float*)d_in[6];
    const float* w_q    = (const float*)d_in[7];
    const float* w_k    = (const float*)d_in[8];
    const float* w_bl   = (const float*)d_in[9];
    const float* w_proj = (const float*)d_in[10];
    const float* b_proj = (const float*)d_in[11];
    float* out = (float*)d_out;
    float* ws  = (float*)d_ws;

    // zero atomic-accumulated regions (ws is poisoned 0xAA before every call)
    hipMemsetAsync(ws + ZERO_OFF, 0, (size_t)ZERO_CNT * sizeof(float), stream);

    k_resize_mask<<<(Bsz * Ssz + 255) / 256, 256, 0, stream>>>(masks, ws);
    k_pool_sn2<<<dim3(4, Cch / CPG, Bsz), 256, 0, stream>>>(supp, ws + OFF_MASK, ws + OFF_SN2);
    k_wmap<<<dim3(4, 6), 256, 0, stream>>>(ws + OFF_SN2, ws + OFF_WMAP);
    k_v<<<dim3(Cch, Bsz), 256, 0, stream>>>(supp, ws);
    k_dot<<<dim3(15, Cch / 64, Bsz), 256, 0, stream>>>(query, ws);
    k_sim<<<6, 256, 0, stream>>>(ws);
    k_final<<<(Bsz * Ssz + 2378 + 255) / 256, 256, 0, stream>>>(weight, ws, out);

    k_apa_u<<<Bsz, 1024, 0, stream>>>(text, proto, w_q, w_bl, w_k, ws);
    k_score<<<dim3(15, 4, Bsz), 256, 0, stream>>>(kin, ws);
    k_softmax<<<Bsz, 256, 0, stream>>>(ws);
    k_kbar<<<dim3(HID, Bsz), 256, 0, stream>>>(kin, ws);
    k_apa_out<<<Bsz, 1024, 0, stream>>>(w_k, w_proj, b_proj, proto, ws, out);
}

// Round 3
// 251.874 us; speedup vs baseline: 1.7179x; 1.4274x over previous
//
#include <hip/hip_runtime.h>
#include <math.h>

#define EPSF 1e-7f
#define Bsz 2
#define Cch 1024
#define Hh 60
#define Ssz 3600
#define HID 256
#define TDIM 300
#define MH 473

// pool tiling
#define TROWS 15
#define LROWS 21          // TROWS + 6 halo
#define LPITCH 68         // 4-offset zero pad on both sides of 60 cols
#define CPG 16            // channels per block

// workspace layout (float offsets). total 93568 floats = 374 KB
#define OFF_MASK  0            // 2*3600   resized masks
#define OFF_SN2   7200         // 6*3600   sum over c of pooled^2  (atomic -> zeroed)
#define OFF_DOT   28800        // 6*3600   dotmaps                 (atomic -> zeroed)
#define OFF_ACC   50400        // 2*3600   normalized-sim accum    (atomic -> zeroed)
#define OFF_SCORE 57600        // 2*3600   attn scores/probs       (atomic -> zeroed)
#define OFF_WMAP  64800        // 6*3600   pool(inv_sn)
#define OFF_V     86400        // 6*1024   v[c] per (b,kt)
#define OFF_U     92544        // 2*256
#define OFF_KBAR  93056        // 2*256
#define ZERO_OFF  OFF_SN2
#define ZERO_CNT  (OFF_WMAP - OFF_SN2)   // 57600 floats

// ---------------- mask bilinear resize 473x473 -> 60x60 (align_corners) ----
__global__ void k_resize_mask(const float* __restrict__ masks, float* __restrict__ ws) {
    int idx = blockIdx.x * 256 + threadIdx.x;
    if (idx >= Bsz * Ssz) return;
    int b = idx / Ssz, q = idx - b * Ssz;
    int y = q / Hh, x = q - y * Hh;
    const float sc = (float)(MH - 1) / (float)(Hh - 1);   // exactly 8.0
    float py = y * sc, px = x * sc;
    int y0 = (int)floorf(py); int y1 = min(y0 + 1, MH - 1); float wy = py - y0;
    int x0 = (int)floorf(px); int x1 = min(x0 + 1, MH - 1); float wx = px - x0;
    const float* m = masks + (size_t)b * MH * MH;
    float v = m[y0 * MH + x0] * (1.f - wy) * (1.f - wx)
            + m[y1 * MH + x0] * wy * (1.f - wx)
            + m[y0 * MH + x1] * (1.f - wy) * wx
            + m[y1 * MH + x1] * wy * wx;
    ws[OFF_MASK + idx] = v;
}

// ---------------- pass A: sn2[b][kt][q] = sum_c pool_kt(supp_c*mask)(q)^2 --
__global__ void __launch_bounds__(256) k_pool_sn2(const float* __restrict__ supp,
                                                  const float* __restrict__ ws_mask,
                                                  float* __restrict__ sn2g) {
    __shared__ float mk[LROWS * LPITCH];
    __shared__ float raw[LROWS * LPITCH];
    __shared__ float hs5[LROWS * LPITCH];
    __shared__ float hs7[LROWS * LPITCH];
    int tid = threadIdx.x;
    int tile = blockIdx.x;       // 0..3
    int cg = blockIdx.y;         // 0..63
    int b = blockIdx.z;          // 0..1
    int y0 = tile * TROWS;

    for (int i = tid; i < LROWS * LPITCH; i += 256) {
        mk[i] = 0.f; raw[i] = 0.f; hs5[i] = 0.f; hs7[i] = 0.f;
    }
    __syncthreads();

    int lr[5], lx[5]; bool lv[5], la[5];
    #pragma unroll
    for (int j = 0; j < 5; ++j) {
        int idx = tid + 256 * j;
        int r = idx / 60, x = idx - 60 * r;
        lr[j] = r; lx[j] = x;
        la[j] = idx < 1260;
        int iy = y0 - 3 + r;
        lv[j] = la[j] && (iy >= 0) && (iy < Hh);
    }
    const float* mrow = ws_mask + (size_t)b * Ssz;
    #pragma unroll
    for (int j = 0; j < 5; ++j)
        if (lv[j]) mk[lr[j] * LPITCH + 4 + lx[j]] = mrow[(y0 - 3 + lr[j]) * 60 + lx[j]];

    int orow[4], ox[4]; bool ov[4];
    #pragma unroll
    for (int j = 0; j < 4; ++j) {
        int o = tid + 256 * j;
        int oy = o / 60, x = o - 60 * oy;
        orow[j] = oy + 3; ox[j] = x; ov[j] = o < 900;
    }
    float a0[4] = {0,0,0,0}, a1[4] = {0,0,0,0}, a2[4] = {0,0,0,0};

    const float* chbase = supp + ((size_t)b * Cch + (size_t)cg * CPG) * Ssz + (y0 - 3) * 60;
    float pf[5];
    #pragma unroll
    for (int j = 0; j < 5; ++j) pf[j] = lv[j] ? chbase[tid + 256 * j] : 0.f;

    for (int c = 0; c < CPG; ++c) {
        __syncthreads();
        #pragma unroll
        for (int j = 0; j < 5; ++j)
            if (lv[j]) raw[lr[j] * LPITCH + 4 + lx[j]] = pf[j] * mk[lr[j] * LPITCH + 4 + lx[j]];
        __syncthreads();
        #pragma unroll
        for (int j = 0; j < 5; ++j)
            if (la[j]) {
                int base = lr[j] * LPITCH + 4 + lx[j];
                float m3 = raw[base - 3], m2 = raw[base - 2], m1 = raw[base - 1];
                float c0 = raw[base], p1 = raw[base + 1], p2 = raw[base + 2], p3 = raw[base + 3];
                float h5 = m2 + m1 + c0 + p1 + p2;
                hs5[base] = h5;
                hs7[base] = h5 + m3 + p3;
            }
        __syncthreads();
        if (c + 1 < CPG) {
            const float* nb = chbase + (size_t)(c + 1) * Ssz;
            #pragma unroll
            for (int j = 0; j < 5; ++j) pf[j] = lv[j] ? nb[tid + 256 * j] : 0.f;
        }
        #pragma unroll
        for (int j = 0; j < 4; ++j)
            if (ov[j]) {
                int base = orow[j] * LPITCH + 4 + ox[j];
                float p55 = hs5[base - 2*LPITCH] + hs5[base - LPITCH] + hs5[base]
                          + hs5[base + LPITCH] + hs5[base + 2*LPITCH];
                float p71 = raw[base - 3*LPITCH] + raw[base - 2*LPITCH] + raw[base - LPITCH]
                          + raw[base] + raw[base + LPITCH] + raw[base + 2*LPITCH] + raw[base + 3*LPITCH];
                float p17 = hs7[base];
                p55 *= (1.f / 25.f); p71 *= (1.f / 7.f); p17 *= (1.f / 7.f);
                a0[j] += p55 * p55; a1[j] += p71 * p71; a2[j] += p17 * p17;
            }
    }
    float* g0 = sn2g + ((size_t)b * 3 + 0) * Ssz;
    float* g1 = sn2g + ((size_t)b * 3 + 1) * Ssz;
    float* g2 = sn2g + ((size_t)b * 3 + 2) * Ssz;
    #pragma unroll
    for (int j = 0; j < 4; ++j)
        if (ov[j]) {
            int q = (y0 + orow[j] - 3) * 60 + ox[j];
            atomicAdd(&g0[q], a0[j]);
            atomicAdd(&g1[q], a1[j]);
            atomicAdd(&g2[q], a2[j]);
        }
}

// ---------------- wmap[b][kt] = pool_kt(1/sn), row-tiled ------------------
__global__ void k_wmap(const float* __restrict__ sn2g, float* __restrict__ wmapg) {
    __shared__ float inv[LROWS * LPITCH];
    int tile = blockIdx.x;       // 0..3
    int bk = blockIdx.y;         // 0..5 = b*3+kt
    int kt = bk % 3;
    int tid = threadIdx.x;
    int y0 = tile * TROWS;
    for (int i = tid; i < LROWS * LPITCH; i += 256) inv[i] = 0.f;
    __syncthreads();
    const float* sn2 = sn2g + (size_t)bk * Ssz;
    #pragma unroll
    for (int j = 0; j < 5; ++j) {
        int idx = tid + 256 * j;
        if (idx < 1260) {
            int r = idx / 60, x = idx - 60 * r;
            int iy = y0 - 3 + r;
            if (iy >= 0 && iy < Hh)
                inv[r * LPITCH + 4 + x] = 1.0f / sqrtf(fmaxf(sn2[iy * 60 + x], 1e-30f));
        }
    }
    __syncthreads();
    int kh = (kt == 0) ? 5 : (kt == 1) ? 7 : 1;
    int kw = (kt == 0) ? 5 : (kt == 2) ? 7 : 1;
    int rh = kh / 2, rw = kw / 2;
    float norm = 1.f / (float)(kh * kw);
    #pragma unroll
    for (int j = 0; j < 4; ++j) {
        int o = tid + 256 * j;
        if (o < 900) {
            int oy = o / 60, x = o - 60 * oy;
            int base = (oy + 3) * LPITCH + 4 + x;
            float s = 0.f;
            for (int dy = -rh; dy <= rh; ++dy)
                for (int dx = -rw; dx <= rw; ++dx)
                    s += inv[base + dy * LPITCH + dx];
            wmapg[(size_t)bk * Ssz + (y0 + oy) * 60 + x] = s * norm;
        }
    }
}

// ---------------- v[b][kt][c] = sum_p supp*mask*wmap ------------------------
__global__ void k_v(const float* __restrict__ supp, float* __restrict__ ws) {
    int c = blockIdx.x, b = blockIdx.y;
    int tid = threadIdx.x;
    const float* sp = supp + ((size_t)b * Cch + c) * Ssz;
    const float* mrow = ws + OFF_MASK + (size_t)b * Ssz;
    const float* w0 = ws + OFF_WMAP + (size_t)(b * 3 + 0) * Ssz;
    const float* w1 = ws + OFF_WMAP + (size_t)(b * 3 + 1) * Ssz;
    const float* w2 = ws + OFF_WMAP + (size_t)(b * 3 + 2) * Ssz;
    float a0 = 0, a1 = 0, a2 = 0;
    for (int q = tid; q < Ssz; q += 256) {
        float s = sp[q] * mrow[q];
        a0 += s * w0[q]; a1 += s * w1[q]; a2 += s * w2[q];
    }
    __shared__ float red[3][256];
    red[0][tid] = a0; red[1][tid] = a1; red[2][tid] = a2;
    __syncthreads();
    for (int off = 128; off > 0; off >>= 1) {
        if (tid < off) {
            red[0][tid] += red[0][tid + off];
            red[1][tid] += red[1][tid + off];
            red[2][tid] += red[2][tid + off];
        }
        __syncthreads();
    }
    if (tid == 0) {
        ws[OFF_V + (size_t)(b * 3 + 0) * Cch + c] = red[0][0];
        ws[OFF_V + (size_t)(b * 3 + 1) * Cch + c] = red[1][0];
        ws[OFF_V + (size_t)(b * 3 + 2) * Cch + c] = red[2][0];
    }
}

// ---------------- dot[b][kt][q] = sum_c query[c,q]*v[kt][c] -----------------
__global__ void k_dot(const float* __restrict__ query, float* __restrict__ ws) {
    int qt = blockIdx.x, cc = blockIdx.y, b = blockIdx.z;
    int q = qt * 256 + threadIdx.x;
    if (q >= Ssz) return;
    const float* v0 = ws + OFF_V + (size_t)(b * 3 + 0) * Cch;
    const float* v1 = ws + OFF_V + (size_t)(b * 3 + 1) * Cch;
    const float* v2 = ws + OFF_V + (size_t)(b * 3 + 2) * Cch;
    float a0 = 0, a1 = 0, a2 = 0;
    int c0 = cc * 64;
    for (int c = c0; c < c0 + 64; ++c) {
        float qv = query[((size_t)b * Cch + c) * Ssz + q];
        a0 += qv * v0[c]; a1 += qv * v1[c]; a2 += qv * v2[c];
    }
    atomicAdd(&ws[OFF_DOT + (size_t)(b * 3 + 0) * Ssz + q], a0);
    atomicAdd(&ws[OFF_DOT + (size_t)(b * 3 + 1) * Ssz + q], a1);
    atomicAdd(&ws[OFF_DOT + (size_t)(b * 3 + 2) * Ssz + q], a2);
}

// ---------------- sim = pool(dot)/(khkw*S); minmax-normalize; accumulate ----
__global__ void k_sim(float* __restrict__ ws) {
    __shared__ float d[Ssz];
    __shared__ float red[256];
    int bk = blockIdx.x; int b = bk / 3; int kt = bk % 3;
    int tid = threadIdx.x;
    const float* dg = ws + OFF_DOT + (size_t)bk * Ssz;
    for (int i = tid; i < Ssz; i += 256) d[i] = dg[i];
    __syncthreads();
    int kh = (kt == 0) ? 5 : (kt == 1) ? 7 : 1;
    int kw = (kt == 0) ? 5 : (kt == 2) ? 7 : 1;
    int rh = kh / 2, rw = kw / 2;
    float norm = 1.f / ((float)(kh * kw) * (float)Ssz);
    float vals[15];
    float vmin = INFINITY, vmax = -INFINITY;
    for (int j = 0; j < 15; ++j) {
        int q = tid + j * 256;
        if (q < Ssz) {
            int y = q / Hh, x = q - y * Hh;
            float s = 0.f;
            for (int dy = -rh; dy <= rh; ++dy) {
                int yy = y + dy; if (yy < 0 || yy >= Hh) continue;
                for (int dx = -rw; dx <= rw; ++dx) {
                    int xx = x + dx; if (xx < 0 || xx >= Hh) continue;
                    s += d[yy * Hh + xx];
                }
            }
            float val = s * norm;
            vals[j] = val;
            vmin = fminf(vmin, val); vmax = fmaxf(vmax, val);
        }
    }
    red[tid] = vmin; __syncthreads();
    for (int off = 128; off > 0; off >>= 1) {
        if (tid < off) red[tid] = fminf(red[tid], red[tid + off]);
        __syncthreads();
    }
    float mn = red[0]; __syncthreads();
    red[tid] = vmax; __syncthreads();
    for (int off = 128; off > 0; off >>= 1) {
        if (tid < off) red[tid] = fmaxf(red[tid], red[tid + off]);
        __syncthreads();
    }
    float mx = red[0];
    float inv = 1.f / (mx - mn + EPSF);
    for (int j = 0; j < 15; ++j) {
        int q = tid + j * 256;
        if (q < Ssz) atomicAdd(&ws[OFF_ACC + (size_t)b * Ssz + q], (vals[j] - mn) * inv);
    }
}

// ---------------- corr1 + bilinear downsamples ------------------------------
__global__ void k_final(const float* __restrict__ weight, const float* __restrict__ ws,
                        float* __restrict__ out) {
    int idx = blockIdx.x * 256 + threadIdx.x;
    if (idx < Bsz * Ssz) {
        int b = idx / Ssz, q = idx - b * Ssz;
        out[idx] = weight[b] * (1.f / 3.f) * ws[OFF_ACC + (size_t)b * Ssz + q];
        return;
    }
    int r = idx - Bsz * Ssz;
    int O, outbase;
    if (r < 1800)       { O = 30; outbase = 7200; }
    else if (r < 2250)  { O = 15; outbase = 9000; r -= 1800; }
    else if (r < 2378)  { O = 8;  outbase = 9450; r -= 2250; }
    else return;
    int n = O * O;
    int b = r / n, p = r - b * n;
    int y = p / O, x = p - y * O;
    float sc = (float)(Hh - 1) / (float)(O - 1);
    float py = y * sc, px = x * sc;
    int y0 = (int)floorf(py), x0 = (int)floorf(px);
    int y1 = min(y0 + 1, Hh - 1), x1 = min(x0 + 1, Hh - 1);
    float wy = py - y0, wx = px - x0;
    const float* src = ws + OFF_ACC + (size_t)b * Ssz;
    float v = src[y0 * Hh + x0] * (1.f - wy) * (1.f - wx)
            + src[y1 * Hh + x0] * wy * (1.f - wx)
            + src[y0 * Hh + x1] * (1.f - wy) * wx
            + src[y1 * Hh + x1] * wy * wx;
    out[outbase + r] = v * weight[b] * (1.f / 3.f);
}

// ---------------- APA: u = w_k^T (w_bl^T (w_q^T [text;proto])) --------------
// grid=2, block=1024 (16 waves). Each stage: lane = float4 column group,
// wave = K partition -> independent unrolled coalesced 16B loads, LDS reduce.
__global__ void __launch_bounds__(1024, 1)
k_apa_u(const float* __restrict__ text, const float* __restrict__ proto,
        const float* __restrict__ w_q, const float* __restrict__ w_bl,
        const float* __restrict__ w_k, float* __restrict__ ws) {
    int b = blockIdx.x;
    int tid = threadIdx.x;
    int lane = tid & 63, w = tid >> 6;        // w = 0..15
    __shared__ float4 p4[16][64];
    __shared__ float qxs[256], qws[256];
    const float4* wq4 = (const float4*)w_q;
    const float4* wbl4 = (const float4*)w_bl;
    const float4* wk4 = (const float4*)w_k;

    // stage 1: qx[h] = sum_e q[e] * w_q[e,h],  E=556
    float4 acc = {0.f, 0.f, 0.f, 0.f};
    #pragma unroll
    for (int j = 0; j < 35; ++j) {
        int e = w + 16 * j;
        if (e < TDIM + HID) {
            float x = (e < TDIM) ? text[b * TDIM + e] : proto[b * HID + e - TDIM];
            float4 f = wq4[(size_t)e * 64 + lane];
            acc.x += x * f.x; acc.y += x * f.y; acc.z += x * f.z; acc.w += x * f.w;
        }
    }
    p4[w][lane] = acc;
    __syncthreads();
    if (tid < 256) {
        const float* pf = (const float*)p4;
        float s = 0.f;
        #pragma unroll
        for (int ww = 0; ww < 16; ++ww) s += pf[ww * 256 + tid];
        qxs[tid] = s;
    }
    __syncthreads();

    // stage 2: qw[h] = sum_e qx[e] * w_bl[e,h], E=256
    acc.x = acc.y = acc.z = acc.w = 0.f;
    #pragma unroll
    for (int j = 0; j < 16; ++j) {
        int e = w + 16 * j;
        float x = qxs[e];
        float4 f = wbl4[(size_t)e * 64 + lane];
        acc.x += x * f.x; acc.y += x * f.y; acc.z += x * f.z; acc.w += x * f.w;
    }
    p4[w][lane] = acc;
    __syncthreads();
    if (tid < 256) {
        const float* pf = (const float*)p4;
        float s = 0.f;
        #pragma unroll
        for (int ww = 0; ww < 16; ++ww) s += pf[ww * 256 + tid];
        qws[tid] = s;
    }
    __syncthreads();

    // stage 3: u[i] = sum_o qw[o] * w_k[o,i], E=256
    acc.x = acc.y = acc.z = acc.w = 0.f;
    #pragma unroll
    for (int j = 0; j < 16; ++j) {
        int e = w + 16 * j;
        float x = qws[e];
        float4 f = wk4[(size_t)e * 64 + lane];
        acc.x += x * f.x; acc.y += x * f.y; acc.z += x * f.z; acc.w += x * f.w;
    }
    p4[w][lane] = acc;
    __syncthreads();
    if (tid < 256) {
        const float* pf = (const float*)p4;
        float s = 0.f;
        #pragma unroll
        for (int ww = 0; ww < 16; ++ww) s += pf[ww * 256 + tid];
        ws[OFF_U + b * HID + tid] = s;
    }
}

// ---------------- score[b,s] = sum_i u[i] * k[b,i,s] ------------------------
__global__ void k_score(const float* __restrict__ kin, float* __restrict__ ws) {
    int st = blockIdx.x, ic = blockIdx.y, b = blockIdx.z;
    int s = st * 256 + threadIdx.x;
    if (s >= Ssz) return;
    const float* u = ws + OFF_U + b * HID;
    float acc = 0.f;
    int i0 = ic * 64;
    for (int i = i0; i < i0 + 64; ++i)
        acc += u[i] * kin[((size_t)b * HID + i) * Ssz + s];
    atomicAdd(&ws[OFF_SCORE + (size_t)b * Ssz + s], acc);
}

// ---------------- softmax over 3600, in place -------------------------------
__global__ void k_softmax(float* __restrict__ ws) {
    int b = blockIdx.x; int tid = threadIdx.x;
    __shared__ float red[256];
    float* sc = ws + OFF_SCORE + (size_t)b * Ssz;
    float vals[15];
    float mx = -INFINITY;
    for (int j = 0; j < 15; ++j) {
        int s = tid + j * 256;
        if (s < Ssz) { vals[j] = sc[s]; mx = fmaxf(mx, vals[j]); }
    }
    red[tid] = mx; __syncthreads();
    for (int off = 128; off > 0; off >>= 1) {
        if (tid < off) red[tid] = fmaxf(red[tid], red[tid + off]);
        __syncthreads();
    }
    mx = red[0]; __syncthreads();
    float sum = 0.f;
    for (int j = 0; j < 15; ++j) {
        int s = tid + j * 256;
        if (s < Ssz) { vals[j] = expf(vals[j] - mx); sum += vals[j]; }
    }
    red[tid] = sum; __syncthreads();
    for (int off = 128; off > 0; off >>= 1) {
        if (tid < off) red[tid] += red[tid + off];
        __syncthreads();
    }
    float inv = 1.f / red[0];
    for (int j = 0; j < 15; ++j) {
        int s = tid + j * 256;
        if (s < Ssz) sc[s] = vals[j] * inv;
    }
}

// ---------------- kbar[b,i] = sum_s p[s]*k[b,i,s] ---------------------------
__global__ void k_kbar(const float* __restrict__ kin, float* __restrict__ ws) {
    int i = blockIdx.x, b = blockIdx.y;
    int tid = threadIdx.x;
    const float* p = ws + OFF_SCORE + (size_t)b * Ssz;
    const float* kr = kin + ((size_t)b * HID + i) * Ssz;
    float acc = 0.f;
    for (int s = tid; s < Ssz; s += 256) acc += p[s] * kr[s];
    __shared__ float red[256];
    red[tid] = acc; __syncthreads();
    for (int off = 128; off > 0; off >>= 1) {
        if (tid < off) red[tid] += red[tid + off];
        __syncthreads();
    }
    if (tid == 0) ws[OFF_KBAR + b * HID + i] = red[0];
}

// ---------------- out = w_proj^T (w_k kbar) + b + proto ---------------------
// grid=2, block=1024. o1 = wave-per-row dot (shuffle reduce);
// o2 = A^T x pattern (float4 lanes, wave K-split, LDS reduce).
__global__ void __launch_bounds__(1024, 1)
k_apa_out(const float* __restrict__ w_k, const float* __restrict__ w_proj,
          const float* __restrict__ b_proj, const float* __restrict__ proto,
          const float* __restrict__ ws, float* __restrict__ out) {
    int b = blockIdx.x;
    int tid = threadIdx.x;
    int lane = tid & 63, w = tid >> 6;
    __shared__ float4 kbs[64];
    __shared__ float o1s[256];
    __shared__ float4 p4[16][64];
    const float4* wk4 = (const float4*)w_k;
    const float4* wp4 = (const float4*)w_proj;

    if (tid < 64) kbs[tid] = ((const float4*)(ws + OFF_KBAR + b * HID))[tid];
    __syncthreads();

    // o1[h] = sum_i w_k[h,i] * kb[i] : wave w handles rows h = w + 16*r
    float4 kb4 = kbs[lane];
    #pragma unroll
    for (int r = 0; r < 16; ++r) {
        int h = w + 16 * r;
        float4 f = wk4[(size_t)h * 64 + lane];
        float p = f.x * kb4.x + f.y * kb4.y + f.z * kb4.z + f.w * kb4.w;
        #pragma unroll
        for (int m = 32; m >= 1; m >>= 1) p += __shfl_xor(p, m, 64);
        if (lane == 0) o1s[h] = p;
    }
    __syncthreads();

    // o2[h] = sum_d o1[d] * w_proj[d,h]
    float4 acc = {0.f, 0.f, 0.f, 0.f};
    #pragma unroll
    for (int j = 0; j < 16; ++j) {
        int d = w + 16 * j;
        float x = o1s[d];
        float4 f = wp4[(size_t)d * 64 + lane];
        acc.x += x * f.x; acc.y += x * f.y; acc.z += x * f.z; acc.w += x * f.w;
    }
    p4[w][lane] = acc;
    __syncthreads();
    if (tid < 256) {
        const float* pf = (const float*)p4;
        float s = 0.f;
        #pragma unroll
        for (int ww = 0; ww < 16; ++ww) s += pf[ww * 256 + tid];
        out[9578 + b * HID + tid] = s + b_proj[tid] + proto[b * HID + tid];
    }
}

extern "C" void kernel_launch(void* const* d_in, const int* in_sizes, int n_in,
                              void* d_out, int out_size, void* d_ws, size_t ws_size,
                              hipStream_t stream) {
    const float* weight = (const float*)d_in[0];
    const float* query  = (const float*)d_in[1];
    const float* supp   = (const float*)d_in[2];
    const float* masks  = (const float*)d_in[3];
    const float* kin    = (const float*)d_in[4];
    const float* text   = (const float*)d_in[5];
    const float* proto  = (const float*)d_in[6];
    const float* w_q    = (const float*)d_in[7];
    const float* w_k    = (const float*)d_in[8];
    const float* w_bl   = (const float*)d_in[9];
    const float* w_proj = (const float*)d_in[10];
    const float* b_proj = (const float*)d_in[11];
    float* out = (float*)d_out;
    float* ws  = (float*)d_ws;

    // zero atomic-accumulated regions (ws is poisoned 0xAA before every call)
    hipMemsetAsync(ws + ZERO_OFF, 0, (size_t)ZERO_CNT * sizeof(float), stream);

    k_resize_mask<<<(Bsz * Ssz + 255) / 256, 256, 0, stream>>>(masks, ws);
    k_pool_sn2<<<dim3(4, Cch / CPG, Bsz), 256, 0, stream>>>(supp, ws + OFF_MASK, ws + OFF_SN2);
    k_wmap<<<dim3(4, 6), 256, 0, stream>>>(ws + OFF_SN2, ws + OFF_WMAP);
    k_v<<<dim3(Cch, Bsz), 256, 0, stream>>>(supp, ws);
    k_dot<<<dim3(15, Cch / 64, Bsz), 256, 0, stream>>>(query, ws);
    k_sim<<<6, 256, 0, stream>>>(ws);
    k_final<<<(Bsz * Ssz + 2378 + 255) / 256, 256, 0, stream>>>(weight, ws, out);

    k_apa_u<<<Bsz, 1024, 0, stream>>>(text, proto, w_q, w_bl, w_k, ws);
    k_score<<<dim3(15, 4, Bsz), 256, 0, stream>>>(kin, ws);
    k_softmax<<<Bsz, 256, 0, stream>>>(ws);
    k_kbar<<<dim3(HID, Bsz), 256, 0, stream>>>(kin, ws);
    k_apa_out<<<Bsz, 1024, 0, stream>>>(w_k, w_proj, b_proj, proto, ws, out);
}